// Round 8
// baseline (651.116 us; speedup 1.0000x reference)
//
#include <hip/hip_runtime.h>
#include <hip/hip_cooperative_groups.h>
#include <math.h>

namespace cg = cooperative_groups;

#define B_ 4
#define N_ 2048
#define H_ 128
#define K_ 32
#define L_ 4
#define OUT_ 6
#define BN_ (B_*N_)
#define GB 512                 // grid blocks (cooperative): needs only 2/CU resident
#define NPB 16                 // nodes per block == MFMA tile rows (no waste)

typedef __attribute__((ext_vector_type(8))) short short8;
typedef __attribute__((ext_vector_type(4))) float f32x4;

#define LDW (H_ + 8)           // padded LDS row (bf16 elems)
#define LAYER_W 98304          // shorts/layer: w1a 16K | w1c 16K | w2 16K | u1 32K | u2 16K
#define OFF_W1A 0
#define OFF_W1C 16384
#define OFF_W2  32768
#define OFF_U1  49152
#define OFF_U2  81920
#define SCAP 256

__device__ __forceinline__ float silu_f(float x) {
    return __fdividef(x, 1.0f + __expf(-x));
}
__device__ __forceinline__ short f2b(float f) {          // fp32 -> bf16 RNE
    unsigned u = __float_as_uint(f);
    return (short)((u + 0x7FFFu + ((u >> 16) & 1u)) >> 16);
}
__device__ __forceinline__ float b2f(short s) {
    return __uint_as_float(((unsigned)(unsigned short)s) << 16);
}
__device__ __forceinline__ unsigned pack2(short lo, short hi) {
    return (unsigned)(unsigned short)lo | ((unsigned)(unsigned short)hi << 16);
}
__device__ __forceinline__ int mbcnt64(unsigned long long m) {
    return __builtin_amdgcn_mbcnt_hi((unsigned)(m >> 32),
           __builtin_amdgcn_mbcnt_lo((unsigned)m, 0));
}

struct Params {
    const float *x, *ew, *eb, *miw, *mib, *mow, *mob, *uiw, *uib, *uow, *uob, *ow, *ob;
    float* out;
    short* c0;         // (BN_, H_) bf16 — double-buffered cross-block tensor
    short* c1;
    short* wt;         // transposed bf16 weights, L_*LAYER_W
};

// knn phase and layer phases never overlap in time -> union.
struct KnnSh { float xsx[N_], xsy[N_], xsz[N_];            // 24 KB
               unsigned skey[4][SCAP]; int sid[4][SCAP]; };// 8 KB
struct LaySh { short s_l[NPB][LDW];    // edge silu-sum; reused for t1
               short h_l[NPB][LDW];    // bf16 h (persists across layers)
               short agg_l[NPB][LDW];};// a (for edge) then agg, alternating
struct OutSh { float h32[NPB][H_]; };  // 8 KB (last layer only)
union ShU { KnnSh knn; LaySh lay; OutSh o; };

__global__ __launch_bounds__(256, 2) void k_mega(Params p)
{
    __shared__ ShU sh;
    __shared__ int   idx_s[NPB][K_];   // knn output, persists for all layers
    __shared__ float dst_s[NPB][K_];

    cg::grid_group grid = cg::this_grid();
    const int tid  = threadIdx.x;
    const int blk  = blockIdx.x;
    const int wave = tid >> 6, lane = tid & 63, l15 = lane & 15, quad = lane >> 4;
    const int node0 = blk * NPB;
    const int batch = node0 / N_;
    const int colbase = wave * 32;

    // ================= Phase P: weight transpose/cast (grid-stride) =================
    for (int gid = blk*256 + tid; gid < L_*LAYER_W; gid += GB*256) {
        int l = gid / LAYER_W, o = gid - l * LAYER_W;
        float v;
        if (o < OFF_W1C) {
            int n = o >> 7, k = o & 127;
            v = p.miw[(size_t)l*257*H_ + k*H_ + n];
        } else if (o < OFF_W2) {
            int oo = o - OFF_W1C, n = oo >> 7, k = oo & 127;
            v = p.miw[(size_t)l*257*H_ + (128 + k)*H_ + n];
        } else if (o < OFF_U1) {
            int oo = o - OFF_W2, n = oo >> 7, k = oo & 127;
            v = p.mow[(size_t)l*H_*H_ + k*H_ + n];
        } else if (o < OFF_U2) {
            int oo = o - OFF_U1, n = oo >> 8, k = oo & 255;
            v = p.uiw[(size_t)l*2*H_*H_ + k*H_ + n];
        } else {
            int oo = o - OFF_U2, n = oo >> 7, k = oo & 127;
            v = p.uow[(size_t)l*H_*H_ + k*H_ + n];
        }
        p.wt[gid] = f2b(v);
    }

    // ================= Phase K: knn for this block's 16 rows (4 per wave) =================
    {
        const float* xb = p.x + (size_t)batch*N_*3;
        for (int t = tid; t < N_*3; t += 256) {
            float v = xb[t];
            int q = t / 3, r = t - q*3;
            float* dst = (r == 0) ? sh.knn.xsx : (r == 1) ? sh.knn.xsy : sh.knn.xsz;
            dst[q] = v;
        }
        __syncthreads();
        for (int rr = 0; rr < NPB/4; ++rr) {
            int lrow = wave*(NPB/4) + rr;           // 0..15
            int i = (node0 % N_) + lrow;            // batch-local row
            float xix = sh.knn.xsx[i], xiy = sh.knn.xsy[i], xiz = sh.knn.xsz[i];

            unsigned u[N_/64];
            unsigned lmin = 0xFFFFFFFFu;
#pragma unroll
            for (int t = 0; t < N_/64; ++t) {
                int j = lane + 64*t;
                float d0 = xix-sh.knn.xsx[j], d1 = xiy-sh.knn.xsy[j], d2 = xiz-sh.knn.xsz[j];
                float d = d0*d0 + d1*d1 + d2*d2;
                unsigned k = (j == i) ? 0x7F800000u : __float_as_uint(d);
                u[t] = k;
                lmin = min(lmin, k);
            }
            unsigned Tup = 0;                        // K-th smallest of lane minima
#pragma unroll
            for (int bit = 30; bit >= 0; --bit) {
                unsigned cand = Tup | (1u << bit);
                if (__popcll(__ballot(lmin < cand)) < K_) Tup = cand;
            }
            unsigned* sk = sh.knn.skey[wave];
            int*      si = sh.knn.sid [wave];
            int base = 0;
#pragma unroll
            for (int t = 0; t < N_/64; ++t) {
                bool pr = (u[t] <= Tup);
                unsigned long long m = __ballot(pr);
                if (pr) {
                    int pos = base + mbcnt64(m);
                    if (pos < SCAP) { sk[pos] = u[t]; si[pos] = lane + 64*t; }
                }
                base += __popcll(m);
            }
            int c = min(base, SCAP);
            unsigned sv[4]; int iv[4];
#pragma unroll
            for (int q = 0; q < 4; ++q) {
                int slot = lane + 64*q;
                bool ok = slot < c;
                sv[q] = ok ? sk[slot] : 0xFFFFFFFFu;
                iv[q] = ok ? si[slot] : 0;
            }
            unsigned T = 0;
#pragma unroll
            for (int bit = 30; bit >= 0; --bit) {
                unsigned cand = T | (1u << bit);
                int cnt = __popcll(__ballot(sv[0] < cand)) + __popcll(__ballot(sv[1] < cand))
                        + __popcll(__ballot(sv[2] < cand)) + __popcll(__ballot(sv[3] < cand));
                if (cnt < K_) T = cand;
            }
            int cnt_lt = __popcll(__ballot(sv[0] < T)) + __popcll(__ballot(sv[1] < T))
                       + __popcll(__ballot(sv[2] < T)) + __popcll(__ballot(sv[3] < T));
            int need = K_ - cnt_lt;
            int ltc = 0, eqc = 0;
#pragma unroll
            for (int q = 0; q < 4; ++q) {
                bool lt = sv[q] < T, eq = sv[q] == T;
                unsigned long long mlt = __ballot(lt), meq = __ballot(eq);
                int pp = ltc + mbcnt64(mlt), ee = eqc + mbcnt64(meq);
                ltc += __popcll(mlt); eqc += __popcll(meq);
                int pos = lt ? pp : ((eq && ee < need) ? (cnt_lt + ee) : -1);
                if (pos >= 0) {
                    idx_s[lrow][pos] = iv[q];
                    dst_s[lrow][pos] = sqrtf(__uint_as_float(sv[q]));
                }
            }
        }
    }
    grid.sync();    // #1: wt visible everywhere (knn outputs are block-local)

    // ================= Phase E0: embed -> h_l + hres(regs); ac(0) -> agg_l + c0 =================
    float hres[2][4];                                // fp32 h, D-tile lane mapping
    for (int t = tid; t < NPB*H_; t += 256) {
        int row = t >> 7, ch = t & 127;
        int gr = node0 + row;
        float v = p.eb[ch];
        v = fmaf(p.x[gr*3+0], p.ew[ch], v);
        v = fmaf(p.x[gr*3+1], p.ew[H_+ch], v);
        v = fmaf(p.x[gr*3+2], p.ew[2*H_+ch], v);
        sh.lay.h_l[row][ch] = f2b(v);
    }
#pragma unroll
    for (int ct = 0; ct < 2; ++ct) {
        int n = colbase + ct*16 + l15;
#pragma unroll
        for (int r = 0; r < 4; ++r) {
            int gr = node0 + quad*4 + r;
            float v = p.eb[n];
            v = fmaf(p.x[gr*3+0], p.ew[n], v);
            v = fmaf(p.x[gr*3+1], p.ew[H_+n], v);
            v = fmaf(p.x[gr*3+2], p.ew[2*H_+n], v);
            hres[ct][r] = v;
        }
    }
    __syncthreads();
    {   // ac(0): a -> agg_l (LDS), c -> c0 (global)
        const short* w1a = p.wt + OFF_W1A;
        const short* w1c = p.wt + OFF_W1C;
        f32x4 accA[2], accC[2];
#pragma unroll
        for (int ct = 0; ct < 2; ++ct) { accA[ct] = (f32x4){0,0,0,0}; accC[ct] = (f32x4){0,0,0,0}; }
#pragma unroll
        for (int kk = 0; kk < 4; ++kk) {
            int k0 = kk*32 + quad*8;
            short8 af = *(const short8*)&sh.lay.h_l[l15][k0];
#pragma unroll
            for (int ct = 0; ct < 2; ++ct) {
                int n = colbase + ct*16 + l15;
                short8 bA = *(const short8*)(w1a + (size_t)n*H_ + k0);
                short8 bC = *(const short8*)(w1c + (size_t)n*H_ + k0);
                accA[ct] = __builtin_amdgcn_mfma_f32_16x16x32_bf16(af, bA, accA[ct], 0, 0, 0);
                accC[ct] = __builtin_amdgcn_mfma_f32_16x16x32_bf16(af, bC, accC[ct], 0, 0, 0);
            }
        }
#pragma unroll
        for (int ct = 0; ct < 2; ++ct) {
            int n = colbase + ct*16 + l15;
            float b1v = p.mib[n];
#pragma unroll
            for (int r = 0; r < 4; ++r) {
                int m = quad*4 + r;
                sh.lay.agg_l[m][n] = f2b(accA[ct][r] + b1v);
                p.c0[(size_t)(node0+m)*H_ + n] = f2b(accC[ct][r]);
            }
        }
    }
    grid.sync();    // #2: c0 visible

    // ================= layers =================
    for (int l = 0; l < L_; ++l) {
        const short* c_rd = (l & 1) ? p.c1 : p.c0;        // read  c(l)
        short*       c_wr = (l & 1) ? p.c0 : p.c1;        // write c(l+1) (other buffer)
        // ---- edge: s_l[m][ch] = sum_k silu(a_i + c_j + d*wd), a in agg_l ----
        {
            const float* wdl = p.miw + (size_t)l*257*H_ + 256*H_;
            float wd0 = wdl[2*lane], wd1 = wdl[2*lane+1];
            const unsigned* c2 = (const unsigned*)c_rd + (size_t)batch*N_*(H_/2);
#pragma unroll
            for (int nn = 0; nn < NPB/4; ++nn) {
                int m = wave*(NPB/4) + nn;
                unsigned av = *(const unsigned*)&sh.lay.agg_l[m][2*lane];
                float a0 = b2f((short)(av & 0xFFFFu)), a1 = b2f((short)(av >> 16));
                float s0 = 0.f, s1 = 0.f;
#pragma unroll 8
                for (int k = 0; k < K_; ++k) {
                    int j = idx_s[m][k];
                    float dd = dst_s[m][k];
                    unsigned cv = c2[(size_t)j*(H_/2) + lane];
                    s0 += silu_f(a0 + fmaf(dd, wd0, b2f((short)(cv & 0xFFFFu))));
                    s1 += silu_f(a1 + fmaf(dd, wd1, b2f((short)(cv >> 16))));
                }
                *(unsigned*)&sh.lay.s_l[m][2*lane] = pack2(f2b(s0), f2b(s1));
            }
        }
        __syncthreads();

        const short* wl = p.wt + (size_t)l*LAYER_W;
        f32x4 acc[2];
        // ---- GEMM1: agg = s @ w2 + K*b2 -> agg_l ----
#pragma unroll
        for (int ct = 0; ct < 2; ++ct) acc[ct] = (f32x4){0,0,0,0};
#pragma unroll
        for (int kk = 0; kk < 4; ++kk) {
            int k0 = kk*32 + quad*8;
            short8 af = *(const short8*)&sh.lay.s_l[l15][k0];
#pragma unroll
            for (int ct = 0; ct < 2; ++ct) {
                int n = colbase + ct*16 + l15;
                short8 bf = *(const short8*)(wl + OFF_W2 + (size_t)n*H_ + k0);
                acc[ct] = __builtin_amdgcn_mfma_f32_16x16x32_bf16(af, bf, acc[ct], 0, 0, 0);
            }
        }
        __syncthreads();   // all s_l reads done before agg_l overwrite... (agg_l aliases a)
#pragma unroll
        for (int ct = 0; ct < 2; ++ct) {
            int n = colbase + ct*16 + l15;
            float b2v = p.mob[(size_t)l*H_ + n] * (float)K_;
#pragma unroll
            for (int r = 0; r < 4; ++r)
                sh.lay.agg_l[quad*4 + r][n] = f2b(acc[ct][r] + b2v);
        }
        __syncthreads();

        // ---- GEMM2: t1 = silu([h | agg] @ u1 + u1b) -> s_l ----
#pragma unroll
        for (int ct = 0; ct < 2; ++ct) acc[ct] = (f32x4){0,0,0,0};
#pragma unroll
        for (int kk = 0; kk < 8; ++kk) {
            const short (*src)[LDW] = (kk < 4) ? sh.lay.h_l : sh.lay.agg_l;
            int kloc = ((kk < 4) ? kk*32 : (kk-4)*32) + quad*8;
            short8 af = *(const short8*)&src[l15][kloc];
#pragma unroll
            for (int ct = 0; ct < 2; ++ct) {
                int n = colbase + ct*16 + l15;
                short8 bf = *(const short8*)(wl + OFF_U1 + (size_t)n*2*H_ + kk*32 + quad*8);
                acc[ct] = __builtin_amdgcn_mfma_f32_16x16x32_bf16(af, bf, acc[ct], 0, 0, 0);
            }
        }
        __syncthreads();
#pragma unroll
        for (int ct = 0; ct < 2; ++ct) {
            int n = colbase + ct*16 + l15;
            float u1bv = p.uib[(size_t)l*H_ + n];
#pragma unroll
            for (int r = 0; r < 4; ++r)
                sh.lay.s_l[quad*4 + r][n] = f2b(silu_f(acc[ct][r] + u1bv));
        }
        __syncthreads();

        // ---- GEMM3: upd = t1 @ u2 ; h(regs) += upd + u2b ----
#pragma unroll
        for (int ct = 0; ct < 2; ++ct) acc[ct] = (f32x4){0,0,0,0};
#pragma unroll
        for (int kk = 0; kk < 4; ++kk) {
            int k0 = kk*32 + quad*8;
            short8 af = *(const short8*)&sh.lay.s_l[l15][k0];
#pragma unroll
            for (int ct = 0; ct < 2; ++ct) {
                int n = colbase + ct*16 + l15;
                short8 bf = *(const short8*)(wl + OFF_U2 + (size_t)n*H_ + k0);
                acc[ct] = __builtin_amdgcn_mfma_f32_16x16x32_bf16(af, bf, acc[ct], 0, 0, 0);
            }
        }
        if (l < L_-1) {
#pragma unroll
            for (int ct = 0; ct < 2; ++ct) {
                int n = colbase + ct*16 + l15;
                float u2bv = p.uob[(size_t)l*H_ + n];
#pragma unroll
                for (int r = 0; r < 4; ++r) {
                    float nh = hres[ct][r] + acc[ct][r] + u2bv;
                    hres[ct][r] = nh;
                    sh.lay.h_l[quad*4 + r][n] = f2b(nh);
                }
            }
            __syncthreads();
            // ---- ac(l+1): a -> agg_l, c -> c_wr ----
            const short* wn = p.wt + (size_t)(l+1)*LAYER_W;
            f32x4 accA[2], accC[2];
#pragma unroll
            for (int ct = 0; ct < 2; ++ct) { accA[ct] = (f32x4){0,0,0,0}; accC[ct] = (f32x4){0,0,0,0}; }
#pragma unroll
            for (int kk = 0; kk < 4; ++kk) {
                int k0 = kk*32 + quad*8;
                short8 af = *(const short8*)&sh.lay.h_l[l15][k0];
#pragma unroll
                for (int ct = 0; ct < 2; ++ct) {
                    int n = colbase + ct*16 + l15;
                    short8 bA = *(const short8*)(wn + OFF_W1A + (size_t)n*H_ + k0);
                    short8 bC = *(const short8*)(wn + OFF_W1C + (size_t)n*H_ + k0);
                    accA[ct] = __builtin_amdgcn_mfma_f32_16x16x32_bf16(af, bA, accA[ct], 0, 0, 0);
                    accC[ct] = __builtin_amdgcn_mfma_f32_16x16x32_bf16(af, bC, accC[ct], 0, 0, 0);
                }
            }
#pragma unroll
            for (int ct = 0; ct < 2; ++ct) {
                int n = colbase + ct*16 + l15;
                float b1v = p.mib[(size_t)(l+1)*H_ + n];
#pragma unroll
                for (int r = 0; r < 4; ++r) {
                    int m = quad*4 + r;
                    sh.lay.agg_l[m][n] = f2b(accA[ct][r] + b1v);
                    c_wr[(size_t)(node0+m)*H_ + n] = f2b(accC[ct][r]);
                }
            }
            grid.sync();           // end of layer l: c(l+1) visible, skew bounded
        } else {
            __syncthreads();       // all s_l reads done before h32 alias-write
#pragma unroll
            for (int ct = 0; ct < 2; ++ct) {
                int n = colbase + ct*16 + l15;
                float u2bv = p.uob[(size_t)l*H_ + n];
#pragma unroll
                for (int r = 0; r < 4; ++r)
                    sh.o.h32[quad*4 + r][n] = hres[ct][r] + acc[ct][r] + u2bv;
            }
            __syncthreads();
            // ---- out: out = h @ ow + ob (fp32, from LDS) ----
            if (tid < NPB*OUT_) {
                int node = tid / OUT_, o = tid - node*OUT_;
                float accv = p.ob[o];
                for (int r = 0; r < H_; ++r)
                    accv = fmaf(sh.o.h32[node][r], p.ow[r*OUT_ + o], accv);
                p.out[(size_t)(node0+node)*OUT_ + o] = accv;
            }
        }
    }
}

extern "C" void kernel_launch(void* const* d_in, const int* in_sizes, int n_in,
                              void* d_out, int out_size, void* d_ws, size_t ws_size,
                              hipStream_t stream)
{
    Params p;
    p.x   = (const float*)d_in[0];
    p.ew  = (const float*)d_in[1];
    p.eb  = (const float*)d_in[2];
    p.miw = (const float*)d_in[3];
    p.mib = (const float*)d_in[4];
    p.mow = (const float*)d_in[5];
    p.mob = (const float*)d_in[6];
    p.uiw = (const float*)d_in[7];
    p.uib = (const float*)d_in[8];
    p.uow = (const float*)d_in[9];
    p.uob = (const float*)d_in[10];
    p.ow  = (const float*)d_in[11];
    p.ob  = (const float*)d_in[12];
    p.out = (float*)d_out;

    char* w = (char*)d_ws;
    p.c0 = (short*)w;                      w += (size_t)BN_*H_*2;     // 2 MB
    p.c1 = (short*)w;                      w += (size_t)BN_*H_*2;     // 2 MB
    p.wt = (short*)w;                                                // 768 KB

    void* args[] = { &p };
    hipLaunchCooperativeKernel((const void*)k_mega, dim3(GB), dim3(256),
                               args, 0, stream);
}

// Round 9
// 330.104 us; speedup vs baseline: 1.9725x; 1.9725x over previous
//
#include <hip/hip_runtime.h>
#include <math.h>

#define B_ 4
#define N_ 2048
#define H_ 128
#define K_ 32
#define L_ 4
#define OUT_ 6
#define BN_ (B_*N_)
#define NPB 16                 // nodes per block in layer/embed kernels

typedef __attribute__((ext_vector_type(8))) short short8;
typedef __attribute__((ext_vector_type(4))) float f32x4;

#define LDW (H_ + 8)           // padded LDS row (bf16 elems)
#define LAYER_W 98304          // shorts/layer: w1a 16K | w1c 16K | w2 16K | u1 32K | u2 16K
#define OFF_W1A 0
#define OFF_W1C 16384
#define OFF_W2  32768
#define OFF_U1  49152
#define OFF_U2  81920
#define SCAP 256

__device__ __forceinline__ float silu_f(float x) {
    return __fdividef(x, 1.0f + __expf(-x));
}
__device__ __forceinline__ short f2b(float f) {          // fp32 -> bf16 RNE
    unsigned u = __float_as_uint(f);
    return (short)((u + 0x7FFFu + ((u >> 16) & 1u)) >> 16);
}
__device__ __forceinline__ float b2f(short s) {
    return __uint_as_float(((unsigned)(unsigned short)s) << 16);
}
__device__ __forceinline__ unsigned pack2(short lo, short hi) {
    return (unsigned)(unsigned short)lo | ((unsigned)(unsigned short)hi << 16);
}
__device__ __forceinline__ int mbcnt64(unsigned long long m) {
    return __builtin_amdgcn_mbcnt_hi((unsigned)(m >> 32),
           __builtin_amdgcn_mbcnt_lo((unsigned)m, 0));
}

// ---------------- prep: transpose+cast all layer weights to bf16 [n][k] ----------------
__global__ __launch_bounds__(256) void k_prep(
    const float* __restrict__ miw, const float* __restrict__ mow,
    const float* __restrict__ uiw, const float* __restrict__ uow,
    short* __restrict__ wt)
{
    int gid = blockIdx.x * 256 + threadIdx.x;      // L_*LAYER_W threads exactly
    int l = gid / LAYER_W, o = gid - l * LAYER_W;
    float v;
    if (o < OFF_W1C) {
        int n = o >> 7, k = o & 127;
        v = miw[(size_t)l*257*H_ + k*H_ + n];
    } else if (o < OFF_W2) {
        int oo = o - OFF_W1C, n = oo >> 7, k = oo & 127;
        v = miw[(size_t)l*257*H_ + (128 + k)*H_ + n];
    } else if (o < OFF_U1) {
        int oo = o - OFF_W2, n = oo >> 7, k = oo & 127;
        v = mow[(size_t)l*H_*H_ + k*H_ + n];
    } else if (o < OFF_U2) {
        int oo = o - OFF_U1, n = oo >> 8, k = oo & 255;
        v = uiw[(size_t)l*2*H_*H_ + k*H_ + n];
    } else {
        int oo = o - OFF_U2, n = oo >> 7, k = oo & 127;
        v = uow[(size_t)l*H_*H_ + k*H_ + n];
    }
    wt[gid] = f2b(v);
}

// ---------------- knn: 3-stage ballot select (R6 version, full grid) ----------------
#define KNN_ROWS 4
__global__ __launch_bounds__(256) void k_knn(
    const float* __restrict__ x, int* __restrict__ nidx, float* __restrict__ ndist)
{
    __shared__ float xsx[N_], xsy[N_], xsz[N_];          // 24 KB
    __shared__ unsigned skey[KNN_ROWS][SCAP];            // 4 KB
    __shared__ int      sid [KNN_ROWS][SCAP];            // 4 KB
    int b  = blockIdx.x / (N_/KNN_ROWS);
    int i0 = (blockIdx.x % (N_/KNN_ROWS)) * KNN_ROWS;
    const float* xb = x + (size_t)b*N_*3;
    for (int t = threadIdx.x; t < N_*3; t += 256) {
        float v = xb[t];
        int q = t / 3, r = t - q*3;
        float* dst = (r == 0) ? xsx : (r == 1) ? xsy : xsz;
        dst[q] = v;
    }
    __syncthreads();

    int wave = threadIdx.x >> 6, lane = threadIdx.x & 63;
    int i = i0 + wave;
    float xix = xsx[i], xiy = xsy[i], xiz = xsz[i];

    unsigned u[N_/64];
    unsigned lmin = 0xFFFFFFFFu;
#pragma unroll
    for (int t = 0; t < N_/64; ++t) {
        int j = lane + 64*t;
        float d0 = xix-xsx[j], d1 = xiy-xsy[j], d2 = xiz-xsz[j];
        float d = d0*d0 + d1*d1 + d2*d2;
        unsigned k = (j == i) ? 0x7F800000u : __float_as_uint(d);
        u[t] = k;
        lmin = min(lmin, k);
    }
    unsigned Tup = 0;
#pragma unroll
    for (int bit = 30; bit >= 0; --bit) {
        unsigned cand = Tup | (1u << bit);
        if (__popcll(__ballot(lmin < cand)) < K_) Tup = cand;
    }
    unsigned* sk = skey[wave];
    int*      si = sid [wave];
    int base = 0;
#pragma unroll
    for (int t = 0; t < N_/64; ++t) {
        bool pr = (u[t] <= Tup);
        unsigned long long m = __ballot(pr);
        if (pr) {
            int pos = base + mbcnt64(m);
            if (pos < SCAP) { sk[pos] = u[t]; si[pos] = lane + 64*t; }
        }
        base += __popcll(m);
    }
    int c = min(base, SCAP);
    unsigned sv[4]; int iv[4];
#pragma unroll
    for (int q = 0; q < 4; ++q) {
        int slot = lane + 64*q;
        bool ok = slot < c;
        sv[q] = ok ? sk[slot] : 0xFFFFFFFFu;
        iv[q] = ok ? si[slot] : 0;
    }
    unsigned T = 0;
#pragma unroll
    for (int bit = 30; bit >= 0; --bit) {
        unsigned cand = T | (1u << bit);
        int cnt = __popcll(__ballot(sv[0] < cand)) + __popcll(__ballot(sv[1] < cand))
                + __popcll(__ballot(sv[2] < cand)) + __popcll(__ballot(sv[3] < cand));
        if (cnt < K_) T = cand;
    }
    int cnt_lt = __popcll(__ballot(sv[0] < T)) + __popcll(__ballot(sv[1] < T))
               + __popcll(__ballot(sv[2] < T)) + __popcll(__ballot(sv[3] < T));
    int need = K_ - cnt_lt;
    size_t rbase = ((size_t)(b*N_ + i)) * K_;
    int ltc = 0, eqc = 0;
#pragma unroll
    for (int q = 0; q < 4; ++q) {
        bool lt = sv[q] < T, eq = sv[q] == T;
        unsigned long long mlt = __ballot(lt), meq = __ballot(eq);
        int pp = ltc + mbcnt64(mlt), ee = eqc + mbcnt64(meq);
        ltc += __popcll(mlt); eqc += __popcll(meq);
        int pos = lt ? pp : ((eq && ee < need) ? (cnt_lt + ee) : -1);
        if (pos >= 0) {
            nidx [rbase + pos] = iv[q];
            ndist[rbase + pos] = sqrtf(__uint_as_float(sv[q]));
        }
    }
}

// ---------------- shared a/c MFMA: from bf16 h in LDS (16 rows) ----------------
__device__ __forceinline__ void ac_mfma_from_lds(
    const short (*h_l)[LDW], int node0, int tid,
    const short* __restrict__ wt1a, const short* __restrict__ wt1c,
    const float* __restrict__ b1,
    short* __restrict__ a, short* __restrict__ c)
{
    int wave = tid >> 6, lane = tid & 63, l15 = lane & 15, quad = lane >> 4;
    f32x4 accA[2], accC[2];
#pragma unroll
    for (int ct = 0; ct < 2; ++ct) {
        accA[ct] = (f32x4){0.f,0.f,0.f,0.f};
        accC[ct] = (f32x4){0.f,0.f,0.f,0.f};
    }
    int colbase = wave * 32;
#pragma unroll
    for (int kk = 0; kk < 4; ++kk) {
        int k0 = kk*32 + quad*8;
        short8 af = *(const short8*)&h_l[l15][k0];
#pragma unroll
        for (int ct = 0; ct < 2; ++ct) {
            int n = colbase + ct*16 + l15;
            short8 bA = *(const short8*)(wt1a + (size_t)n*H_ + k0);
            short8 bC = *(const short8*)(wt1c + (size_t)n*H_ + k0);
            accA[ct] = __builtin_amdgcn_mfma_f32_16x16x32_bf16(af, bA, accA[ct], 0, 0, 0);
            accC[ct] = __builtin_amdgcn_mfma_f32_16x16x32_bf16(af, bC, accC[ct], 0, 0, 0);
        }
    }
#pragma unroll
    for (int ct = 0; ct < 2; ++ct) {
        int n = colbase + ct*16 + l15;
        float b1v = b1[n];
#pragma unroll
        for (int r = 0; r < 4; ++r) {
            int m = quad*4 + r;
            size_t gi = (size_t)(node0+m)*H_ + n;
            a[gi] = f2b(accA[ct][r] + b1v);
            c[gi] = f2b(accC[ct][r]);
        }
    }
}

// ---------------- embed + layer-0 a/c (grid 512) ----------------
__global__ __launch_bounds__(256) void k_embed_ac(
    const float* __restrict__ x, const float* __restrict__ ew,
    const float* __restrict__ eb,
    const short* __restrict__ wt1a, const short* __restrict__ wt1c,
    const float* __restrict__ b1,
    float* __restrict__ h, short* __restrict__ a, short* __restrict__ c)
{
    __shared__ __align__(16) short h_l[NPB][LDW];
    int node0 = blockIdx.x * NPB;
    int tid = threadIdx.x;
    for (int t = tid; t < NPB*H_; t += 256) {
        int row = t >> 7, ch = t & 127;
        int gr = node0 + row;
        float v = eb[ch];
        v = fmaf(x[gr*3+0], ew[ch], v);
        v = fmaf(x[gr*3+1], ew[H_+ch], v);
        v = fmaf(x[gr*3+2], ew[2*H_+ch], v);
        h[(size_t)gr*H_ + ch] = v;
        h_l[row][ch] = f2b(v);
    }
    __syncthreads();
    ac_mfma_from_lds(h_l, node0, tid, wt1a, wt1c, b1, a, c);
}

// ---------------- k_layer: edge + 3 GEMMs + residual + ac(l+1), 16 nodes/block ----------------
__global__ __launch_bounds__(256) void k_layer(
    float* __restrict__ h, short* __restrict__ a,
    const int* __restrict__ nidx, const float* __restrict__ ndist,
    const float* __restrict__ wd,
    const short* __restrict__ wl,          // layer weights base (wt + l*LAYER_W)
    const float* __restrict__ b2, const float* __restrict__ u1b,
    const float* __restrict__ u2b,
    const short* __restrict__ c_rd, short* __restrict__ c_wr,
    const short* __restrict__ wn, const float* __restrict__ b1n, int do_ac)
{
    __shared__ __align__(16) short s_l[NPB][LDW];    // edge silu-sum; reused for t1
    __shared__ __align__(16) short h_l[NPB][LDW];    // bf16 h (old, then new)
    __shared__ __align__(16) short agg_l[NPB][LDW];
    __shared__ int   idx_s[NPB][K_];
    __shared__ float dst_s[NPB][K_];
    int node0 = blockIdx.x * NPB;
    int batch = node0 / N_;
    int tid = threadIdx.x;
    int wave = tid >> 6, lane = tid & 63, l15 = lane & 15, quad = lane >> 4;
    int colbase = wave * 32;

    // stage h (fp32->bf16) + idx/dist
    for (int t = tid; t < NPB*H_/4; t += 256) {
        float4 v = reinterpret_cast<const float4*>(h + (size_t)node0*H_)[t];
        int row = t >> 5, col = (t & 31) * 4;
        h_l[row][col+0] = f2b(v.x); h_l[row][col+1] = f2b(v.y);
        h_l[row][col+2] = f2b(v.z); h_l[row][col+3] = f2b(v.w);
    }
    for (int t = tid; t < NPB*K_; t += 256) {
        idx_s[t>>5][t&31] = nidx[(size_t)node0*K_ + t];
        dst_s[t>>5][t&31] = ndist[(size_t)node0*K_ + t];
    }
    __syncthreads();

    // ---- edge: s_l[m][ch] = sum_k silu(a_i + c_j + d*wd) ----
    {
        float wd0 = wd[2*lane], wd1 = wd[2*lane+1];
        const unsigned* c2 = (const unsigned*)c_rd + (size_t)batch*N_*(H_/2);
        const unsigned* a2 = (const unsigned*)a;
#pragma unroll
        for (int nn = 0; nn < NPB/4; ++nn) {
            int m = wave*(NPB/4) + nn;
            unsigned av = a2[(size_t)(node0+m)*(H_/2) + lane];
            float a0 = b2f((short)(av & 0xFFFFu)), a1 = b2f((short)(av >> 16));
            float s0 = 0.f, s1 = 0.f;
#pragma unroll 8
            for (int k = 0; k < K_; ++k) {
                int j = idx_s[m][k];
                float dd = dst_s[m][k];
                unsigned cv = c2[(size_t)j*(H_/2) + lane];
                s0 += silu_f(a0 + fmaf(dd, wd0, b2f((short)(cv & 0xFFFFu))));
                s1 += silu_f(a1 + fmaf(dd, wd1, b2f((short)(cv >> 16))));
            }
            *(unsigned*)&s_l[m][2*lane] = pack2(f2b(s0), f2b(s1));
        }
    }
    __syncthreads();

    f32x4 acc[2];
    // ---- GEMM1: agg = s @ w2 + K*b2 -> agg_l ----
#pragma unroll
    for (int ct = 0; ct < 2; ++ct) acc[ct] = (f32x4){0,0,0,0};
#pragma unroll
    for (int kk = 0; kk < 4; ++kk) {
        int k0 = kk*32 + quad*8;
        short8 af = *(const short8*)&s_l[l15][k0];
#pragma unroll
        for (int ct = 0; ct < 2; ++ct) {
            int n = colbase + ct*16 + l15;
            short8 bf = *(const short8*)(wl + OFF_W2 + (size_t)n*H_ + k0);
            acc[ct] = __builtin_amdgcn_mfma_f32_16x16x32_bf16(af, bf, acc[ct], 0, 0, 0);
        }
    }
#pragma unroll
    for (int ct = 0; ct < 2; ++ct) {
        int n = colbase + ct*16 + l15;
        float b2v = b2[n] * (float)K_;
#pragma unroll
        for (int r = 0; r < 4; ++r)
            agg_l[quad*4 + r][n] = f2b(acc[ct][r] + b2v);
    }
    __syncthreads();

    // ---- GEMM2: t1 = silu([h | agg] @ u1 + u1b) -> s_l ----
#pragma unroll
    for (int ct = 0; ct < 2; ++ct) acc[ct] = (f32x4){0,0,0,0};
#pragma unroll
    for (int kk = 0; kk < 8; ++kk) {
        const short (*src)[LDW] = (kk < 4) ? h_l : agg_l;
        int kloc = ((kk < 4) ? kk*32 : (kk-4)*32) + quad*8;
        short8 af = *(const short8*)&src[l15][kloc];
#pragma unroll
        for (int ct = 0; ct < 2; ++ct) {
            int n = colbase + ct*16 + l15;
            short8 bf = *(const short8*)(wl + OFF_U1 + (size_t)n*2*H_ + kk*32 + quad*8);
            acc[ct] = __builtin_amdgcn_mfma_f32_16x16x32_bf16(af, bf, acc[ct], 0, 0, 0);
        }
    }
#pragma unroll
    for (int ct = 0; ct < 2; ++ct) {
        int n = colbase + ct*16 + l15;
        float u1bv = u1b[n];
#pragma unroll
        for (int r = 0; r < 4; ++r)
            s_l[quad*4 + r][n] = f2b(silu_f(acc[ct][r] + u1bv));
    }
    __syncthreads();

    // ---- GEMM3: upd = t1 @ u2 + u2b ; h += upd (fp32) ; h_l <- new h (bf16) ----
#pragma unroll
    for (int ct = 0; ct < 2; ++ct) acc[ct] = (f32x4){0,0,0,0};
#pragma unroll
    for (int kk = 0; kk < 4; ++kk) {
        int k0 = kk*32 + quad*8;
        short8 af = *(const short8*)&s_l[l15][k0];
#pragma unroll
        for (int ct = 0; ct < 2; ++ct) {
            int n = colbase + ct*16 + l15;
            short8 bf = *(const short8*)(wl + OFF_U2 + (size_t)n*H_ + k0);
            acc[ct] = __builtin_amdgcn_mfma_f32_16x16x32_bf16(af, bf, acc[ct], 0, 0, 0);
        }
    }
#pragma unroll
    for (int ct = 0; ct < 2; ++ct) {
        int n = colbase + ct*16 + l15;
        float u2bv = u2b[n];
#pragma unroll
        for (int r = 0; r < 4; ++r) {
            int m = quad*4 + r;
            size_t gi = (size_t)(node0+m)*H_ + n;
            float nh = h[gi] + acc[ct][r] + u2bv;
            h[gi] = nh;
            h_l[m][n] = f2b(nh);
        }
    }
    // ---- ac(l+1): a -> global, c -> c_wr (other parity buffer) ----
    if (do_ac) {
        __syncthreads();
        ac_mfma_from_lds(h_l, node0, tid, wn + OFF_W1A, wn + OFF_W1C, b1n, a, c_wr);
    }
}

// ---------------- out: out = h @ ow + ob ----------------
__global__ __launch_bounds__(256) void k_out(
    const float* __restrict__ h, const float* __restrict__ ow,
    const float* __restrict__ ob, float* __restrict__ out)
{
    int gid = blockIdx.x * 256 + threadIdx.x;  // BN_*8 threads
    int node = gid >> 3, o = gid & 7;
    if (o < OUT_) {
        float acc = ob[o];
        const float* hrow = h + (size_t)node*H_;
        for (int r = 0; r < H_; ++r)
            acc = fmaf(hrow[r], ow[r*OUT_ + o], acc);
        out[(size_t)node*OUT_ + o] = acc;
    }
}

extern "C" void kernel_launch(void* const* d_in, const int* in_sizes, int n_in,
                              void* d_out, int out_size, void* d_ws, size_t ws_size,
                              hipStream_t stream)
{
    const float* x   = (const float*)d_in[0];
    const float* ew  = (const float*)d_in[1];
    const float* eb  = (const float*)d_in[2];
    const float* miw = (const float*)d_in[3];
    const float* mib = (const float*)d_in[4];
    const float* mow = (const float*)d_in[5];
    const float* mob = (const float*)d_in[6];
    const float* uiw = (const float*)d_in[7];
    const float* uib = (const float*)d_in[8];
    const float* uow = (const float*)d_in[9];
    const float* uob = (const float*)d_in[10];
    const float* ow  = (const float*)d_in[11];
    const float* ob  = (const float*)d_in[12];
    float* out = (float*)d_out;

    // workspace: h fp32 | nd fp32 | ni i32 | a bf16 | c0 bf16 | c1 bf16 | wt bf16
    char* w = (char*)d_ws;
    float* h  = (float*)w;                         w += (size_t)BN_*H_*4;
    float* nd = (float*)w;                         w += (size_t)BN_*K_*4;
    int*   ni = (int*)w;                           w += (size_t)BN_*K_*4;
    short* a  = (short*)w;                         w += (size_t)BN_*H_*2;
    short* c0 = (short*)w;                         w += (size_t)BN_*H_*2;
    short* c1 = (short*)w;                         w += (size_t)BN_*H_*2;
    short* wt = (short*)w;

    k_prep<<<(L_*LAYER_W)/256, 256, 0, stream>>>(miw, mow, uiw, uow, wt);
    k_knn<<<BN_/KNN_ROWS, 256, 0, stream>>>(x, ni, nd);
    k_embed_ac<<<BN_/NPB, 256, 0, stream>>>(x, ew, eb,
        wt + OFF_W1A, wt + OFF_W1C, mib, h, a, c0);
    for (int l = 0; l < L_; ++l) {
        const short* c_rd = (l & 1) ? c1 : c0;
        short*       c_wr = (l & 1) ? c0 : c1;
        int do_ac = (l + 1 < L_);
        const short* wn = wt + (size_t)(do_ac ? (l+1) : l) * LAYER_W;
        const float* b1n = mib + (size_t)(do_ac ? (l+1) : l) * H_;
        k_layer<<<BN_/NPB, 256, 0, stream>>>(h, a, ni, nd,
            miw + (size_t)l*257*H_ + 256*H_,
            wt + (size_t)l*LAYER_W,
            mob + (size_t)l*H_, uib + (size_t)l*H_, uob + (size_t)l*H_,
            c_rd, c_wr, wn, b1n, do_ac);
    }
    k_out<<<BN_*8/256, 256, 0, stream>>>(h, ow, ob, out);
}

// Round 10
// 277.169 us; speedup vs baseline: 2.3492x; 1.1910x over previous
//
#include <hip/hip_runtime.h>
#include <math.h>

#define B_ 4
#define N_ 2048
#define H_ 128
#define K_ 32
#define L_ 4
#define OUT_ 6
#define BN_ (B_*N_)
#define NPB 16                 // nodes per block in layer/embed kernels
#define LBLK 512               // threads per layer/embed block (8 waves)

typedef __attribute__((ext_vector_type(8))) short short8;
typedef __attribute__((ext_vector_type(4))) float f32x4;

#define LDW (H_ + 8)           // padded LDS row (bf16 elems)
#define LAYER_W 98304          // shorts/layer: w1a 16K | w1c 16K | w2 16K | u1 32K | u2 16K
#define OFF_W1A 0
#define OFF_W1C 16384
#define OFF_W2  32768
#define OFF_U1  49152
#define OFF_U2  81920
#define SCAP 256

__device__ __forceinline__ float silu_f(float x) {
    return __fdividef(x, 1.0f + __expf(-x));
}
__device__ __forceinline__ short f2b(float f) {          // fp32 -> bf16 RNE
    unsigned u = __float_as_uint(f);
    return (short)((u + 0x7FFFu + ((u >> 16) & 1u)) >> 16);
}
__device__ __forceinline__ float b2f(short s) {
    return __uint_as_float(((unsigned)(unsigned short)s) << 16);
}
__device__ __forceinline__ unsigned pack2(short lo, short hi) {
    return (unsigned)(unsigned short)lo | ((unsigned)(unsigned short)hi << 16);
}
__device__ __forceinline__ int mbcnt64(unsigned long long m) {
    return __builtin_amdgcn_mbcnt_hi((unsigned)(m >> 32),
           __builtin_amdgcn_mbcnt_lo((unsigned)m, 0));
}

// ---------------- prep: transpose+cast all layer weights to bf16 [n][k] ----------------
__global__ __launch_bounds__(256) void k_prep(
    const float* __restrict__ miw, const float* __restrict__ mow,
    const float* __restrict__ uiw, const float* __restrict__ uow,
    short* __restrict__ wt)
{
    int gid = blockIdx.x * 256 + threadIdx.x;      // L_*LAYER_W threads exactly
    int l = gid / LAYER_W, o = gid - l * LAYER_W;
    float v;
    if (o < OFF_W1C) {
        int n = o >> 7, k = o & 127;
        v = miw[(size_t)l*257*H_ + k*H_ + n];
    } else if (o < OFF_W2) {
        int oo = o - OFF_W1C, n = oo >> 7, k = oo & 127;
        v = miw[(size_t)l*257*H_ + (128 + k)*H_ + n];
    } else if (o < OFF_U1) {
        int oo = o - OFF_W2, n = oo >> 7, k = oo & 127;
        v = mow[(size_t)l*H_*H_ + k*H_ + n];
    } else if (o < OFF_U2) {
        int oo = o - OFF_U1, n = oo >> 8, k = oo & 255;
        v = uiw[(size_t)l*2*H_*H_ + k*H_ + n];
    } else {
        int oo = o - OFF_U2, n = oo >> 7, k = oo & 127;
        v = uow[(size_t)l*H_*H_ + k*H_ + n];
    }
    wt[gid] = f2b(v);
}

// ---------------- knn: 3-stage ballot select (unchanged from R9) ----------------
#define KNN_ROWS 4
__global__ __launch_bounds__(256) void k_knn(
    const float* __restrict__ x, int* __restrict__ nidx, float* __restrict__ ndist)
{
    __shared__ float xsx[N_], xsy[N_], xsz[N_];          // 24 KB
    __shared__ unsigned skey[KNN_ROWS][SCAP];            // 4 KB
    __shared__ int      sid [KNN_ROWS][SCAP];            // 4 KB
    int b  = blockIdx.x / (N_/KNN_ROWS);
    int i0 = (blockIdx.x % (N_/KNN_ROWS)) * KNN_ROWS;
    const float* xb = x + (size_t)b*N_*3;
    for (int t = threadIdx.x; t < N_*3; t += 256) {
        float v = xb[t];
        int q = t / 3, r = t - q*3;
        float* dst = (r == 0) ? xsx : (r == 1) ? xsy : xsz;
        dst[q] = v;
    }
    __syncthreads();

    int wave = threadIdx.x >> 6, lane = threadIdx.x & 63;
    int i = i0 + wave;
    float xix = xsx[i], xiy = xsy[i], xiz = xsz[i];

    unsigned u[N_/64];
    unsigned lmin = 0xFFFFFFFFu;
#pragma unroll
    for (int t = 0; t < N_/64; ++t) {
        int j = lane + 64*t;
        float d0 = xix-xsx[j], d1 = xiy-xsy[j], d2 = xiz-xsz[j];
        float d = d0*d0 + d1*d1 + d2*d2;
        unsigned k = (j == i) ? 0x7F800000u : __float_as_uint(d);
        u[t] = k;
        lmin = min(lmin, k);
    }
    unsigned Tup = 0;
#pragma unroll
    for (int bit = 30; bit >= 0; --bit) {
        unsigned cand = Tup | (1u << bit);
        if (__popcll(__ballot(lmin < cand)) < K_) Tup = cand;
    }
    unsigned* sk = skey[wave];
    int*      si = sid [wave];
    int base = 0;
#pragma unroll
    for (int t = 0; t < N_/64; ++t) {
        bool pr = (u[t] <= Tup);
        unsigned long long m = __ballot(pr);
        if (pr) {
            int pos = base + mbcnt64(m);
            if (pos < SCAP) { sk[pos] = u[t]; si[pos] = lane + 64*t; }
        }
        base += __popcll(m);
    }
    int c = min(base, SCAP);
    unsigned sv[4]; int iv[4];
#pragma unroll
    for (int q = 0; q < 4; ++q) {
        int slot = lane + 64*q;
        bool ok = slot < c;
        sv[q] = ok ? sk[slot] : 0xFFFFFFFFu;
        iv[q] = ok ? si[slot] : 0;
    }
    unsigned T = 0;
#pragma unroll
    for (int bit = 30; bit >= 0; --bit) {
        unsigned cand = T | (1u << bit);
        int cnt = __popcll(__ballot(sv[0] < cand)) + __popcll(__ballot(sv[1] < cand))
                + __popcll(__ballot(sv[2] < cand)) + __popcll(__ballot(sv[3] < cand));
        if (cnt < K_) T = cand;
    }
    int cnt_lt = __popcll(__ballot(sv[0] < T)) + __popcll(__ballot(sv[1] < T))
               + __popcll(__ballot(sv[2] < T)) + __popcll(__ballot(sv[3] < T));
    int need = K_ - cnt_lt;
    size_t rbase = ((size_t)(b*N_ + i)) * K_;
    int ltc = 0, eqc = 0;
#pragma unroll
    for (int q = 0; q < 4; ++q) {
        bool lt = sv[q] < T, eq = sv[q] == T;
        unsigned long long mlt = __ballot(lt), meq = __ballot(eq);
        int pp = ltc + mbcnt64(mlt), ee = eqc + mbcnt64(meq);
        ltc += __popcll(mlt); eqc += __popcll(meq);
        int pos = lt ? pp : ((eq && ee < need) ? (cnt_lt + ee) : -1);
        if (pos >= 0) {
            nidx [rbase + pos] = iv[q];
            ndist[rbase + pos] = sqrtf(__uint_as_float(sv[q]));
        }
    }
}

// ---------------- shared a/c MFMA: 8 waves, each owns a 16-col strip ----------------
__device__ __forceinline__ void ac_mfma_from_lds(
    const short (*h_l)[LDW], int node0, int tid,
    const short* __restrict__ wt1a, const short* __restrict__ wt1c,
    const float* __restrict__ b1,
    short* __restrict__ a, short* __restrict__ c)
{
    int wave = tid >> 6, lane = tid & 63, l15 = lane & 15, quad = lane >> 4;
    int n = wave*16 + l15;
    f32x4 accA = (f32x4){0.f,0.f,0.f,0.f};
    f32x4 accC = (f32x4){0.f,0.f,0.f,0.f};
#pragma unroll
    for (int kk = 0; kk < 4; ++kk) {
        int k0 = kk*32 + quad*8;
        short8 af = *(const short8*)&h_l[l15][k0];
        short8 bA = *(const short8*)(wt1a + (size_t)n*H_ + k0);
        short8 bC = *(const short8*)(wt1c + (size_t)n*H_ + k0);
        accA = __builtin_amdgcn_mfma_f32_16x16x32_bf16(af, bA, accA, 0, 0, 0);
        accC = __builtin_amdgcn_mfma_f32_16x16x32_bf16(af, bC, accC, 0, 0, 0);
    }
    float b1v = b1[n];
#pragma unroll
    for (int r = 0; r < 4; ++r) {
        int m = quad*4 + r;
        size_t gi = (size_t)(node0+m)*H_ + n;
        a[gi] = f2b(accA[r] + b1v);
        c[gi] = f2b(accC[r]);
    }
}

// ---------------- embed + layer-0 a/c (grid 512 x 512thr) ----------------
__global__ __launch_bounds__(LBLK) void k_embed_ac(
    const float* __restrict__ x, const float* __restrict__ ew,
    const float* __restrict__ eb,
    const short* __restrict__ wt1a, const short* __restrict__ wt1c,
    const float* __restrict__ b1,
    float* __restrict__ h, short* __restrict__ a, short* __restrict__ c)
{
    __shared__ __align__(16) short h_l[NPB][LDW];
    int node0 = blockIdx.x * NPB;
    int tid = threadIdx.x;
    for (int t = tid; t < NPB*H_; t += LBLK) {
        int row = t >> 7, ch = t & 127;
        int gr = node0 + row;
        float v = eb[ch];
        v = fmaf(x[gr*3+0], ew[ch], v);
        v = fmaf(x[gr*3+1], ew[H_+ch], v);
        v = fmaf(x[gr*3+2], ew[2*H_+ch], v);
        h[(size_t)gr*H_ + ch] = v;
        h_l[row][ch] = f2b(v);
    }
    __syncthreads();
    ac_mfma_from_lds(h_l, node0, tid, wt1a, wt1c, b1, a, c);
}

// ---------------- k_layer: edge + 3 GEMMs + residual + ac(l+1) ----------------
// 16 nodes/block, 512 threads (8 waves): wave owns 2 edge nodes + a 16-col
// GEMM strip. Grid 512 -> 2 blocks/CU -> 16 waves/CU (R9 had 8: TLP-starved).
__global__ __launch_bounds__(LBLK) void k_layer(
    float* __restrict__ h, short* __restrict__ a,
    const int* __restrict__ nidx, const float* __restrict__ ndist,
    const float* __restrict__ wd,
    const short* __restrict__ wl,          // layer weights base (wt + l*LAYER_W)
    const float* __restrict__ b2, const float* __restrict__ u1b,
    const float* __restrict__ u2b,
    const short* __restrict__ c_rd, short* __restrict__ c_wr,
    const short* __restrict__ wn, const float* __restrict__ b1n, int do_ac)
{
    __shared__ __align__(16) short s_l[NPB][LDW];    // edge silu-sum; reused for t1
    __shared__ __align__(16) short h_l[NPB][LDW];    // bf16 h (old, then new)
    __shared__ __align__(16) short agg_l[NPB][LDW];
    __shared__ int   idx_s[NPB][K_];
    __shared__ float dst_s[NPB][K_];
    int node0 = blockIdx.x * NPB;
    int batch = node0 / N_;
    int tid = threadIdx.x;
    int wave = tid >> 6, lane = tid & 63, l15 = lane & 15, quad = lane >> 4;
    int ncol = wave*16 + l15;               // this wave's output column

    // stage h (fp32->bf16) + idx/dist
    for (int t = tid; t < NPB*H_/4; t += LBLK) {
        float4 v = reinterpret_cast<const float4*>(h + (size_t)node0*H_)[t];
        int row = t >> 5, col = (t & 31) * 4;
        h_l[row][col+0] = f2b(v.x); h_l[row][col+1] = f2b(v.y);
        h_l[row][col+2] = f2b(v.z); h_l[row][col+3] = f2b(v.w);
    }
    if (tid < NPB*K_) {
        idx_s[tid>>5][tid&31] = nidx[(size_t)node0*K_ + tid];
        dst_s[tid>>5][tid&31] = ndist[(size_t)node0*K_ + tid];
    }
    __syncthreads();

    // ---- edge: s_l[m][ch] = sum_k silu(a_i + c_j + d*wd), 2 nodes/wave ----
    {
        float wd0 = wd[2*lane], wd1 = wd[2*lane+1];
        const unsigned* c2 = (const unsigned*)c_rd + (size_t)batch*N_*(H_/2);
        const unsigned* a2 = (const unsigned*)a;
#pragma unroll
        for (int nn = 0; nn < 2; ++nn) {
            int m = wave*2 + nn;
            unsigned av = a2[(size_t)(node0+m)*(H_/2) + lane];
            float a0 = b2f((short)(av & 0xFFFFu)), a1 = b2f((short)(av >> 16));
            float s0 = 0.f, s1 = 0.f;
#pragma unroll 8
            for (int k = 0; k < K_; ++k) {
                int j = idx_s[m][k];
                float dd = dst_s[m][k];
                unsigned cv = c2[(size_t)j*(H_/2) + lane];
                s0 += silu_f(a0 + fmaf(dd, wd0, b2f((short)(cv & 0xFFFFu))));
                s1 += silu_f(a1 + fmaf(dd, wd1, b2f((short)(cv >> 16))));
            }
            *(unsigned*)&s_l[m][2*lane] = pack2(f2b(s0), f2b(s1));
        }
    }
    __syncthreads();

    f32x4 acc;
    // ---- GEMM1: agg = s @ w2 + K*b2 -> agg_l ----
    acc = (f32x4){0,0,0,0};
#pragma unroll
    for (int kk = 0; kk < 4; ++kk) {
        int k0 = kk*32 + quad*8;
        short8 af = *(const short8*)&s_l[l15][k0];
        short8 bf = *(const short8*)(wl + OFF_W2 + (size_t)ncol*H_ + k0);
        acc = __builtin_amdgcn_mfma_f32_16x16x32_bf16(af, bf, acc, 0, 0, 0);
    }
    {
        float b2v = b2[ncol] * (float)K_;
#pragma unroll
        for (int r = 0; r < 4; ++r)
            agg_l[quad*4 + r][ncol] = f2b(acc[r] + b2v);
    }
    __syncthreads();

    // ---- GEMM2: t1 = silu([h | agg] @ u1 + u1b) -> s_l ----
    acc = (f32x4){0,0,0,0};
#pragma unroll
    for (int kk = 0; kk < 8; ++kk) {
        const short (*src)[LDW] = (kk < 4) ? h_l : agg_l;
        int kloc = ((kk < 4) ? kk*32 : (kk-4)*32) + quad*8;
        short8 af = *(const short8*)&src[l15][kloc];
        short8 bf = *(const short8*)(wl + OFF_U1 + (size_t)ncol*2*H_ + kk*32 + quad*8);
        acc = __builtin_amdgcn_mfma_f32_16x16x32_bf16(af, bf, acc, 0, 0, 0);
    }
    __syncthreads();
    {
        float u1bv = u1b[ncol];
#pragma unroll
        for (int r = 0; r < 4; ++r)
            s_l[quad*4 + r][ncol] = f2b(silu_f(acc[r] + u1bv));
    }
    __syncthreads();

    // ---- GEMM3: upd = t1 @ u2 + u2b ; h += upd (fp32) ; h_l <- new h (bf16) ----
    acc = (f32x4){0,0,0,0};
#pragma unroll
    for (int kk = 0; kk < 4; ++kk) {
        int k0 = kk*32 + quad*8;
        short8 af = *(const short8*)&s_l[l15][k0];
        short8 bf = *(const short8*)(wl + OFF_U2 + (size_t)ncol*H_ + k0);
        acc = __builtin_amdgcn_mfma_f32_16x16x32_bf16(af, bf, acc, 0, 0, 0);
    }
    {
        float u2bv = u2b[ncol];
#pragma unroll
        for (int r = 0; r < 4; ++r) {
            int m = quad*4 + r;
            size_t gi = (size_t)(node0+m)*H_ + ncol;
            float nh = h[gi] + acc[r] + u2bv;
            h[gi] = nh;
            h_l[m][ncol] = f2b(nh);
        }
    }
    // ---- ac(l+1): a -> global, c -> c_wr (other parity buffer) ----
    if (do_ac) {
        __syncthreads();
        ac_mfma_from_lds(h_l, node0, tid, wn + OFF_W1A, wn + OFF_W1C, b1n, a, c_wr);
    }
}

// ---------------- out: out = h @ ow + ob ----------------
__global__ __launch_bounds__(256) void k_out(
    const float* __restrict__ h, const float* __restrict__ ow,
    const float* __restrict__ ob, float* __restrict__ out)
{
    int gid = blockIdx.x * 256 + threadIdx.x;  // BN_*8 threads
    int node = gid >> 3, o = gid & 7;
    if (o < OUT_) {
        float acc = ob[o];
        const float* hrow = h + (size_t)node*H_;
        for (int r = 0; r < H_; ++r)
            acc = fmaf(hrow[r], ow[r*OUT_ + o], acc);
        out[(size_t)node*OUT_ + o] = acc;
    }
}

extern "C" void kernel_launch(void* const* d_in, const int* in_sizes, int n_in,
                              void* d_out, int out_size, void* d_ws, size_t ws_size,
                              hipStream_t stream)
{
    const float* x   = (const float*)d_in[0];
    const float* ew  = (const float*)d_in[1];
    const float* eb  = (const float*)d_in[2];
    const float* miw = (const float*)d_in[3];
    const float* mib = (const float*)d_in[4];
    const float* mow = (const float*)d_in[5];
    const float* mob = (const float*)d_in[6];
    const float* uiw = (const float*)d_in[7];
    const float* uib = (const float*)d_in[8];
    const float* uow = (const float*)d_in[9];
    const float* uob = (const float*)d_in[10];
    const float* ow  = (const float*)d_in[11];
    const float* ob  = (const float*)d_in[12];
    float* out = (float*)d_out;

    // workspace: h fp32 | nd fp32 | ni i32 | a bf16 | c0 bf16 | c1 bf16 | wt bf16
    char* w = (char*)d_ws;
    float* h  = (float*)w;                         w += (size_t)BN_*H_*4;
    float* nd = (float*)w;                         w += (size_t)BN_*K_*4;
    int*   ni = (int*)w;                           w += (size_t)BN_*K_*4;
    short* a  = (short*)w;                         w += (size_t)BN_*H_*2;
    short* c0 = (short*)w;                         w += (size_t)BN_*H_*2;
    short* c1 = (short*)w;                         w += (size_t)BN_*H_*2;
    short* wt = (short*)w;

    k_prep<<<(L_*LAYER_W)/256, 256, 0, stream>>>(miw, mow, uiw, uow, wt);
    k_knn<<<BN_/KNN_ROWS, 256, 0, stream>>>(x, ni, nd);
    k_embed_ac<<<BN_/NPB, LBLK, 0, stream>>>(x, ew, eb,
        wt + OFF_W1A, wt + OFF_W1C, mib, h, a, c0);
    for (int l = 0; l < L_; ++l) {
        const short* c_rd = (l & 1) ? c1 : c0;
        short*       c_wr = (l & 1) ? c0 : c1;
        int do_ac = (l + 1 < L_);
        const short* wn = wt + (size_t)(do_ac ? (l+1) : l) * LAYER_W;
        const float* b1n = mib + (size_t)(do_ac ? (l+1) : l) * H_;
        k_layer<<<BN_/NPB, LBLK, 0, stream>>>(h, a, ni, nd,
            miw + (size_t)l*257*H_ + 256*H_,
            wt + (size_t)l*LAYER_W,
            mob + (size_t)l*H_, uib + (size_t)l*H_, uob + (size_t)l*H_,
            c_rd, c_wr, wn, b1n, do_ac);
    }
    k_out<<<BN_*8/256, 256, 0, stream>>>(h, ow, ob, out);
}